// Round 4
// baseline (102.310 us; speedup 1.0000x reference)
//
#include <hip/hip_runtime.h>
#include <hip/hip_bf16.h>

#define TT  2048
#define NH  32
#define NKV 8
#define DD  128
#define KVB 64          // keys per LDS tile

typedef __attribute__((ext_vector_type(8))) short  short8;
typedef __attribute__((ext_vector_type(4))) float  f32x4;
typedef unsigned int u32;

static __device__ __forceinline__ short f2bf(float x) {
  __bf16 b = (__bf16)x;                 // RNE f32->bf16
  return __builtin_bit_cast(short, b);
}
static __device__ __forceinline__ short8 cvt8(f32x4 a, f32x4 b) {
  short8 r;
  r[0]=f2bf(a[0]); r[1]=f2bf(a[1]); r[2]=f2bf(a[2]); r[3]=f2bf(a[3]);
  r[4]=f2bf(b[0]); r[5]=f2bf(b[1]); r[6]=f2bf(b[2]); r[7]=f2bf(b[3]);
  return r;
}
static __device__ __forceinline__ void gload_lds16(const short* g, short* l) {
  __builtin_amdgcn_global_load_lds(
      (const __attribute__((address_space(1))) u32*)g,
      (__attribute__((address_space(3))) u32*)l, 16, 0, 0);
}

// ---------------- pre-pass: K -> bf16 [kvh][j][d]; V -> bf16 transposed [kvh][d][j] ----
__global__ __launch_bounds__(256) void preconv(
    const float* __restrict__ K, const float* __restrict__ V,
    short* __restrict__ Kbf, short* __restrict__ Vtbf)
{
  const int t = threadIdx.x;
  if (blockIdx.x >= 256) {
    // K[j][kvh][d] f32 -> Kbf[kvh][j][d] bf16 (linear copy-convert)
    const int b  = blockIdx.x - 256;
    const int rr = (b << 6) + (t >> 2);      // rr = j*8+kvh, 0..16383
    const int q  = t & 3;
    const int j = rr >> 3, kvh = rr & 7;
    const float* src = K + (size_t)rr * DD + q * 32;
    short* dst = Kbf + ((size_t)kvh * TT + j) * DD + q * 32;
#pragma unroll
    for (int i = 0; i < 4; ++i) {
      f32x4 a  = *reinterpret_cast<const f32x4*>(src + i * 8);
      f32x4 bb = *reinterpret_cast<const f32x4*>(src + i * 8 + 4);
      *reinterpret_cast<short8*>(dst + i * 8) = cvt8(a, bb);
    }
  } else {
    // V[j][kvh][d] f32 -> Vtbf[kvh][d][j] bf16 via LDS-roundtrip transpose
    const int kvh = blockIdx.x >> 5, jt = blockIdx.x & 31;
    __shared__ short Vl[64][136];
    const int jl = t >> 2, q = t & 3;
    const float* src = V + ((size_t)(jt * 64 + jl) * NKV + kvh) * DD + q * 32;
#pragma unroll
    for (int i = 0; i < 4; ++i) {
      f32x4 a  = *reinterpret_cast<const f32x4*>(src + i * 8);
      f32x4 bb = *reinterpret_cast<const f32x4*>(src + i * 8 + 4);
      *reinterpret_cast<short8*>(&Vl[jl][q * 32 + i * 8]) = cvt8(a, bb);
    }
    __syncthreads();
    const int d = t >> 1, jh = t & 1;
    short8 o[4];
#pragma unroll
    for (int k = 0; k < 4; ++k)
#pragma unroll
      for (int i = 0; i < 8; ++i)
        o[k][i] = Vl[jh * 32 + k * 8 + i][d];
    short* dst = Vtbf + ((size_t)kvh * DD + d) * TT + jt * 64 + jh * 32;
#pragma unroll
    for (int k = 0; k < 4; ++k)
      *reinterpret_cast<short8*>(dst + k * 8) = o[k];
  }
}

// ---------------- main attention kernel ------------------------------------------
// Block = one kv-head x 32 Q-rows x 4 GQA heads. 8 waves.
// K/V double-buffered in LDS, staged by global_load_lds (no regs, no cvt):
// 4 DMA instrs/wave/tile, issued right after the single per-tile barrier,
// landing a full compute phase later. 16B-chunk XOR swizzle (chunk ^= row&7,
// low 3 bits) applied on the per-lane GLOBAL source address (LDS dest linear)
// and on the LDS read side -> all frag reads minimum-cycle, conflict-free.
// LDS: Kb 2x16K + Vt 2x16K + Pl 16K = 80KB exactly -> 2 blocks/CU.
// MFMA 16x16x32 bf16. A-frag: lane holds A[row=l&15][k=8*(l>>4)+i].
// B-frag: lane holds B[k=8*(l>>4)+i][col=l&15].
// C/D:    lane holds C[row=(l>>4)*4+r][col=l&15].
__global__ __launch_bounds__(512, 4) void attn_fwd(
    const float* __restrict__ Q, const short* __restrict__ Kbf,
    const short* __restrict__ Vtbf, float* __restrict__ O,
    float* __restrict__ Mo, float* __restrict__ Lo)
{
  __shared__ __align__(16) short Kb[2][KVB][DD];    // 256B/row, chunk-swizzled
  __shared__ __align__(16) short Vt[2][DD][KVB];    // 128B/row, chunk-swizzled
  __shared__ __align__(16) short Pl[8][16][64];     // per-wave P, chunk-swizzled

  const int bid  = blockIdx.x;
  const int kvh  = bid & (NKV - 1);          // kvh == XCD id under round-robin
  const int jj   = bid >> 3;                 // 0..63
  // heavy+light pairing: blocks c and c+256 share a CU (2 blocks/CU resident)
  const int q32  = (jj < 32) ? (63 - jj) : (jj - 32);
  const int wv   = threadIdx.x >> 6;         // 0..7
  const int lane = threadIdx.x & 63;
  const int l15  = lane & 15;
  const int g4   = lane >> 4;
  const int head = kvh * 4 + (wv & 3);
  const int qbase = q32 * 32 + (wv >> 2) * 16;
  const int e    = (g4 ^ l15) & 7;           // read-side swizzle key

  // staging source offsets (loop-invariant, shorts)
  const int jr0 = (wv << 3) + (lane >> 4);                 // K rows i=0
  const int ck0 = (lane & 8) | ((lane & 7) ^ (lane >> 4));
  const int ck1 = (lane & 8) | ((lane & 7) ^ (lane >> 4) ^ 4);
  const int koff0 = jr0 * DD + ck0 * 8;
  const int koff1 = (jr0 + 4) * DD + ck1 * 8;
  const int dr0 = (wv << 4) + (lane >> 3);                 // V d-rows i=0
  const int cv  = (lane & 7) ^ ((lane >> 3) & 7);
  const int voff0 = dr0 * TT + cv * 8;
  const int voff1 = voff0 + 8 * TT;

  // ---- Q fragments: lane holds Q[qbase+(l&15)][32*ks + 8*g4 + i] ----
  short8 aq[4];
  {
    const float* qp = Q + ((size_t)(qbase + l15) * NH + head) * DD;
#pragma unroll
    for (int ks = 0; ks < 4; ++ks) {
      const float* p = qp + ks * 32 + g4 * 8;
      aq[ks] = cvt8(*reinterpret_cast<const f32x4*>(p),
                    *reinterpret_cast<const f32x4*>(p + 4));
    }
  }

  f32x4 acc[8];
#pragma unroll
  for (int i = 0; i < 8; ++i) acc[i] = (f32x4)0.0f;
  float m[4], lsum[4];
#pragma unroll
  for (int r = 0; r < 4; ++r) { m[r] = -INFINITY; lsum[r] = 0.0f; }

  const int ntiles = (q32 * 32 + 95) >> 6;   // ceil((qbase+16)/64), same both row-groups

  const short* kg = Kbf + (size_t)kvh * TT * DD;     // tile-0 base
  const short* vg = Vtbf + (size_t)kvh * DD * TT;

  // ---- prologue: DMA tile 0 into buffer 0 ----
  gload_lds16(kg + koff0, &Kb[0][(wv << 3)][0]);
  gload_lds16(kg + koff1, &Kb[0][(wv << 3) + 4][0]);
  gload_lds16(vg + voff0, &Vt[0][(wv << 4)][0]);
  gload_lds16(vg + voff1, &Vt[0][(wv << 4) + 8][0]);
  kg += (size_t)KVB * DD;   // -> next tile
  vg += KVB;

  for (int jt = 0; jt < ntiles; ++jt) {
    const int j0 = jt << 6;
    const int buf = jt & 1;

    // single barrier per tile: drains this wave's DMA (vmcnt0) for tile jt,
    // and guarantees everyone finished reading buf^1 (tile jt-1)
    __syncthreads();

    // ---- DMA tile jt+1 into buf^1 (lands during this tile's compute) ----
    if (jt + 1 < ntiles) {
      const int nb = buf ^ 1;
      gload_lds16(kg + koff0, &Kb[nb][(wv << 3)][0]);
      gload_lds16(kg + koff1, &Kb[nb][(wv << 3) + 4][0]);
      gload_lds16(vg + voff0, &Vt[nb][(wv << 4)][0]);
      gload_lds16(vg + voff1, &Vt[nb][(wv << 4) + 8][0]);
      kg += (size_t)KVB * DD;
      vg += KVB;
    }

    // ---- QK^T: S[16 x 64] as four 16-col C/D frags ----
    const short* kb0 = &Kb[buf][l15][e * 8];         // ks even chunks
    const short* kb1 = &Kb[buf][l15][(e ^ 4) * 8];   // ks odd chunks
    f32x4 s[4];
#pragma unroll
    for (int c = 0; c < 4; ++c) s[c] = (f32x4)0.0f;
    __builtin_amdgcn_s_setprio(1);
#pragma unroll
    for (int c = 0; c < 4; ++c) {
      s[c] = __builtin_amdgcn_mfma_f32_16x16x32_bf16(
          aq[0], *reinterpret_cast<const short8*>(kb0 + c * 2048), s[c], 0, 0, 0);
      s[c] = __builtin_amdgcn_mfma_f32_16x16x32_bf16(
          aq[1], *reinterpret_cast<const short8*>(kb1 + c * 2048), s[c], 0, 0, 0);
      s[c] = __builtin_amdgcn_mfma_f32_16x16x32_bf16(
          aq[2], *reinterpret_cast<const short8*>(kb0 + c * 2048 + 64), s[c], 0, 0, 0);
      s[c] = __builtin_amdgcn_mfma_f32_16x16x32_bf16(
          aq[3], *reinterpret_cast<const short8*>(kb1 + c * 2048 + 64), s[c], 0, 0, 0);
    }
    __builtin_amdgcn_s_setprio(0);

    // ---- causal mask: only the last tile can cross the diagonal ----
    if (jt == ntiles - 1) {
#pragma unroll
      for (int c = 0; c < 4; ++c)
#pragma unroll
        for (int r = 0; r < 4; ++r)
          if (j0 + c * 16 + l15 > qbase + g4 * 4 + r) s[c][r] = -1.0e10f;
    }

    // ---- online softmax over the 64-key tile ----
    float sc[4];
#pragma unroll
    for (int r = 0; r < 4; ++r) {
      float t = fmaxf(fmaxf(s[0][r], s[1][r]), fmaxf(s[2][r], s[3][r]));
      t = fmaxf(t, __shfl_xor(t, 1));
      t = fmaxf(t, __shfl_xor(t, 2));
      t = fmaxf(t, __shfl_xor(t, 4));
      t = fmaxf(t, __shfl_xor(t, 8));
      float mn = fmaxf(m[r], t);
      sc[r] = __expf(m[r] - mn);
      m[r] = mn;
      lsum[r] *= sc[r];
    }
#pragma unroll
    for (int c = 0; c < 4; ++c)
#pragma unroll
      for (int r = 0; r < 4; ++r) {
        float p = __expf(s[c][r] - m[r]);
        lsum[r] += p;
        // P[row=g4*4+r][col=c*16+l15], chunk-swizzled: phys = (col>>3)^(row&7)
        const int pch = ((c << 1) | (l15 >> 3)) ^ (((g4 & 1) << 2) | r);
        Pl[wv][g4 * 4 + r][pch * 8 + (l15 & 7)] = f2bf(p);
      }
    f32x4 sv; sv[0]=sc[0]; sv[1]=sc[1]; sv[2]=sc[2]; sv[3]=sc[3];
#pragma unroll
    for (int dt = 0; dt < 8; ++dt) acc[dt] = acc[dt] * sv;

    // ---- P @ V: K-dim = 64 keys, 8 d-tiles ----
    short8 pa0 = *reinterpret_cast<const short8*>(&Pl[wv][l15][e * 8]);
    short8 pa1 = *reinterpret_cast<const short8*>(&Pl[wv][l15][(e ^ 4) * 8]);
    const short* vb0 = &Vt[buf][l15][e * 8];
    const short* vb1 = &Vt[buf][l15][(e ^ 4) * 8];
    __builtin_amdgcn_s_setprio(1);
#pragma unroll
    for (int dt = 0; dt < 8; ++dt) {
      acc[dt] = __builtin_amdgcn_mfma_f32_16x16x32_bf16(
          pa0, *reinterpret_cast<const short8*>(vb0 + dt * 1024), acc[dt], 0, 0, 0);
      acc[dt] = __builtin_amdgcn_mfma_f32_16x16x32_bf16(
          pa1, *reinterpret_cast<const short8*>(vb1 + dt * 1024), acc[dt], 0, 0, 0);
    }
    __builtin_amdgcn_s_setprio(0);
  }

  // ---- epilogue ----
#pragma unroll
  for (int r = 0; r < 4; ++r) {
    float t = lsum[r];
    t += __shfl_xor(t, 1);
    t += __shfl_xor(t, 2);
    t += __shfl_xor(t, 4);
    t += __shfl_xor(t, 8);
    lsum[r] = t;
  }

#pragma unroll
  for (int dt = 0; dt < 8; ++dt)
#pragma unroll
    for (int r = 0; r < 4; ++r) {
      const int qrow = qbase + g4 * 4 + r;
      O[((size_t)qrow * NH + head) * DD + dt * 16 + l15] = acc[dt][r];
    }

  if (l15 == 0) {
#pragma unroll
    for (int r = 0; r < 4; ++r) {
      const int qrow = qbase + g4 * 4 + r;
      Mo[(size_t)qrow * NH + head] = m[r];
      Lo[(size_t)qrow * NH + head] = lsum[r];
    }
  }
}

extern "C" void kernel_launch(void* const* d_in, const int* in_sizes, int n_in,
                              void* d_out, int out_size, void* d_ws, size_t ws_size,
                              hipStream_t stream) {
  const float* Q = (const float*)d_in[0];
  const float* K = (const float*)d_in[1];
  const float* V = (const float*)d_in[2];
  float* O  = (float*)d_out;
  float* Mo = O + (size_t)TT * NH * DD;
  float* Lo = Mo + (size_t)TT * NH;
  short* Kbf  = (short*)d_ws;                          // 4 MB
  short* Vtbf = Kbf + (size_t)NKV * TT * DD;           // 4 MB
  preconv<<<dim3(512), dim3(256), 0, stream>>>(K, V, Kbf, Vtbf);
  attn_fwd<<<dim3(64 * NKV), dim3(512), 0, stream>>>(Q, Kbf, Vtbf, O, Mo, Lo);
}

// Round 6
// 88.355 us; speedup vs baseline: 1.1579x; 1.1579x over previous
//
#include <hip/hip_runtime.h>
#include <hip/hip_bf16.h>

#define TT  2048
#define NH  32
#define NKV 8
#define DD  128
#define KVB 64          // keys per LDS tile

typedef __attribute__((ext_vector_type(8)))  short  short8;
typedef __attribute__((ext_vector_type(4)))  float  f32x4;
typedef __attribute__((ext_vector_type(16))) float  f32x16;
typedef unsigned int u32;
typedef __attribute__((ext_vector_type(4)))  u32    u32x4;

static __device__ __forceinline__ short f2bf(float x) {
  __bf16 b = (__bf16)x;                 // RNE f32->bf16
  return __builtin_bit_cast(short, b);
}
static __device__ __forceinline__ short8 cvt8(f32x4 a, f32x4 b) {
  short8 r;
  r[0]=f2bf(a[0]); r[1]=f2bf(a[1]); r[2]=f2bf(a[2]); r[3]=f2bf(a[3]);
  r[4]=f2bf(b[0]); r[5]=f2bf(b[1]); r[6]=f2bf(b[2]); r[7]=f2bf(b[3]);
  return r;
}
static __device__ __forceinline__ u32 pk2(float lo, float hi) {
  const u32 a = (u32)(unsigned short)f2bf(lo);
  const u32 b = (u32)(unsigned short)f2bf(hi);
  return a | (b << 16);
}
static __device__ __forceinline__ void gload_lds16(const short* g, short* l) {
  __builtin_amdgcn_global_load_lds(
      (const __attribute__((address_space(1))) u32*)g,
      (__attribute__((address_space(3))) u32*)l, 16, 0, 0);
}

// ---------------- pre-pass: K -> bf16 [kvh][j][d]; V -> bf16 transposed [kvh][d][j] ----
__global__ __launch_bounds__(256) void preconv(
    const float* __restrict__ K, const float* __restrict__ V,
    short* __restrict__ Kbf, short* __restrict__ Vtbf)
{
  const int t = threadIdx.x;
  if (blockIdx.x >= 256) {
    const int b  = blockIdx.x - 256;
    const int rr = (b << 6) + (t >> 2);      // rr = j*8+kvh
    const int q  = t & 3;
    const int j = rr >> 3, kvh = rr & 7;
    const float* src = K + (size_t)rr * DD + q * 32;
    short* dst = Kbf + ((size_t)kvh * TT + j) * DD + q * 32;
#pragma unroll
    for (int i = 0; i < 4; ++i) {
      f32x4 a  = *reinterpret_cast<const f32x4*>(src + i * 8);
      f32x4 bb = *reinterpret_cast<const f32x4*>(src + i * 8 + 4);
      *reinterpret_cast<short8*>(dst + i * 8) = cvt8(a, bb);
    }
  } else {
    const int kvh = blockIdx.x >> 5, jt = blockIdx.x & 31;
    __shared__ short Vl[64][136];
    const int jl = t >> 2, q = t & 3;
    const float* src = V + ((size_t)(jt * 64 + jl) * NKV + kvh) * DD + q * 32;
#pragma unroll
    for (int i = 0; i < 4; ++i) {
      f32x4 a  = *reinterpret_cast<const f32x4*>(src + i * 8);
      f32x4 bb = *reinterpret_cast<const f32x4*>(src + i * 8 + 4);
      *reinterpret_cast<short8*>(&Vl[jl][q * 32 + i * 8]) = cvt8(a, bb);
    }
    __syncthreads();
    const int d = t >> 1, jh = t & 1;
    short8 o[4];
#pragma unroll
    for (int k = 0; k < 4; ++k)
#pragma unroll
      for (int i = 0; i < 8; ++i)
        o[k][i] = Vl[jh * 32 + k * 8 + i][d];
    short* dst = Vtbf + ((size_t)kvh * DD + d) * TT + jt * 64 + jh * 32;
#pragma unroll
    for (int k = 0; k < 4; ++k)
      *reinterpret_cast<short8*>(dst + k * 8) = o[k];
  }
}

// ---------------- main attention kernel ------------------------------------------
// Block = one kv-head x 32 Q-rows x 4 GQA heads; 4 waves (wave = 1 head, 32 rows,
// full 64-key tile). MFMA 32x32x16, SWAPPED QK^T: St = mfma(A=K, B=Q) so each lane
// owns one q-column -> softmax max/exp are lane-local VALU. Cross-half (lane^32)
// exchanges use __shfl_xor ONLY (verified semantics; round-5's permlane/cvt_pk asm
// was the prime correctness suspect and is removed).
// K/V double-buffered, staged by global_load_lds with 16B-chunk XOR swizzle
// (phys_chunk = logical ^ (row&7)) pre-applied on the global source address;
// reads apply the same XOR -> conflict-free. LDS = 64KB -> 2 blocks/CU.
// 32x32x16 layouts: A: lane=A[row=l&31][k=8*(l>>5)+i]; B: B[k=8*(l>>5)+i][col=l&31];
// C/D: col=l&31, row=(reg&3)+8*(reg>>2)+4*(l>>5)  [measured m74/m101].
__global__ __launch_bounds__(256, 2) void attn_fwd(
    const float* __restrict__ Q, const short* __restrict__ Kbf,
    const short* __restrict__ Vtbf, float* __restrict__ O,
    float* __restrict__ Mo, float* __restrict__ Lo)
{
  __shared__ __align__(16) short Kb[2][KVB][DD];    // [key][d], 16 chunks/row
  __shared__ __align__(16) short Vt[2][DD][KVB];    // [d][key], 8 chunks/row

  const int bid  = blockIdx.x;
  const int kvh  = bid & (NKV - 1);          // kvh == XCD id under round-robin
  const int jj   = bid >> 3;                 // 0..63
  // heavy+light pairing: blocks c and c+256 share a CU; pair-sum of tiles = const
  const int q32  = (jj < 32) ? (63 - jj) : (jj - 32);
  const int wv   = threadIdx.x >> 6;         // 0..3
  const int lane = threadIdx.x & 63;
  const int l31  = lane & 31;
  const int hiK  = lane >> 5;
  const int l7   = lane & 7;
  const int head = kvh * 4 + wv;
  const int qbase = q32 * 32;
  const int q    = qbase + l31;              // this lane's q-column

  // ---- staging offsets (loop-invariant) ----
  // K: seg t covers rows 16wv+4t..+3; lane -> row +(l>>4), phys chunk l&15,
  //    logical = phys ^ (row&7), row&7 = 4*(t&1)+(l>>4)
  int koff[4];
#pragma unroll
  for (int t = 0; t < 4; ++t) {
    const int row = 16 * wv + 4 * t + (lane >> 4);
    const int ch  = (lane & 15) ^ (4 * (t & 1) + (lane >> 4));
    koff[t] = row * DD + ch * 8;
  }
  // V: seg t covers d-rows 32wv+8t..+7; lane -> row +(l>>3), phys chunk l&7,
  //    logical = phys ^ (row&7) = (l&7)^(l>>3)
  const int vrow0 = 32 * wv + (lane >> 3);
  const int vch   = (lane & 7) ^ (lane >> 3);
  const int voffB = vrow0 * TT + vch * 8;

  // ---- Q B-frags: lane holds Q[qbase+l31][ks*16 + 8*hiK + i], ks=0..7 ----
  short8 aq[8];
  {
    const float* qp = Q + ((size_t)q * NH + head) * DD + hiK * 8;
#pragma unroll
    for (int ks = 0; ks < 8; ++ks) {
      const float* p = qp + ks * 16;
      aq[ks] = cvt8(*reinterpret_cast<const f32x4*>(p),
                    *reinterpret_cast<const f32x4*>(p + 4));
    }
  }

  f32x16 acc[4];
#pragma unroll
  for (int i = 0; i < 4; ++i) acc[i] = (f32x16)0.0f;
  float m = -INFINITY, lsum = 0.0f;

  const int ntiles = (q32 >> 1) + 1;   // ceil((qbase+32)/64)

  const short* kgp = Kbf + (size_t)kvh * TT * DD;
  const short* vgp = Vtbf + (size_t)kvh * DD * TT;

  // ---- prologue: DMA tile 0 into buffer 0 ----
#pragma unroll
  for (int t = 0; t < 4; ++t)
    gload_lds16(kgp + koff[t], &Kb[0][16 * wv + 4 * t][0]);
#pragma unroll
  for (int t = 0; t < 4; ++t)
    gload_lds16(vgp + voffB + t * 8 * TT, &Vt[0][32 * wv + 8 * t][0]);
  kgp += (size_t)KVB * DD;
  vgp += KVB;

  for (int jt = 0; jt < ntiles; ++jt) {
    const int j0  = jt << 6;
    const int buf = jt & 1;

    __syncthreads();   // drains this wave's DMA (vmcnt0); prev buffer free

    // ---- DMA tile jt+1 into buf^1 (lands during this tile's compute) ----
    if (jt + 1 < ntiles) {
      const int nb = buf ^ 1;
#pragma unroll
      for (int t = 0; t < 4; ++t)
        gload_lds16(kgp + koff[t], &Kb[nb][16 * wv + 4 * t][0]);
#pragma unroll
      for (int t = 0; t < 4; ++t)
        gload_lds16(vgp + voffB + t * 8 * TT, &Vt[nb][32 * wv + 8 * t][0]);
      kgp += (size_t)KVB * DD;
      vgp += KVB;
    }

    // ---- QK^T (swapped): st[kg] = S^T[key=kg*32+row(reg,hiK)][q=l31] ----
    f32x16 st[2];
    st[0] = (f32x16)0.0f; st[1] = (f32x16)0.0f;
    __builtin_amdgcn_s_setprio(1);
#pragma unroll
    for (int kg = 0; kg < 2; ++kg) {
      const short* kr = &Kb[buf][kg * 32 + l31][0];
#pragma unroll
      for (int ks = 0; ks < 8; ++ks) {
        const int c = ((ks << 1) | hiK) ^ l7;
        short8 kb = *reinterpret_cast<const short8*>(kr + c * 8);
        st[kg] = __builtin_amdgcn_mfma_f32_32x32x16_bf16(kb, aq[ks], st[kg], 0, 0, 0);
      }
    }
    __builtin_amdgcn_s_setprio(0);

    // ---- causal mask: only the last tile can cross the diagonal ----
    if (jt == ntiles - 1) {
#pragma unroll
      for (int kg = 0; kg < 2; ++kg)
#pragma unroll
        for (int r = 0; r < 16; ++r) {
          const int key = j0 + kg * 32 + (r & 3) + 8 * (r >> 2) + 4 * hiK;
          if (key > q) st[kg][r] = -1.0e10f;
        }
    }

    // ---- lane-local max over 32 keys + cross-half exchange ----
    float mx = fmaxf(st[0][0], st[1][0]);
#pragma unroll
    for (int r = 1; r < 16; ++r) mx = fmaxf(mx, fmaxf(st[0][r], st[1][r]));
    mx = fmaxf(mx, __shfl_xor(mx, 32, 64));

    // ---- rescale only when the running max grows (wave-uniform gate) ----
    if (__any(mx > m)) {
      const float mn = fmaxf(m, mx);
      const float sc = __expf(m - mn);
      m = mn;
      lsum *= sc;
#pragma unroll
      for (int r = 0; r < 16; ++r) {
        const float sf = __shfl(sc, (r & 3) + 8 * (r >> 2) + 4 * hiK, 64);
        acc[0][r] *= sf; acc[1][r] *= sf; acc[2][r] *= sf; acc[3][r] *= sf;
      }
    }

    // ---- P = exp(S-m); redistribute to PV A-frags via lane^32 exchange ----
    // pa[ks][i] must hold P[q=l31][key = 16*ks + 8*hiK + i].
    short8 pa[4];
#pragma unroll
    for (int kg = 0; kg < 2; ++kg) {
      float e[16];
#pragma unroll
      for (int r = 0; r < 16; ++r) e[r] = __expf(st[kg][r] - m);
      lsum += (((e[0]+e[1])+(e[2]+e[3]))+((e[4]+e[5])+(e[6]+e[7])))
            + (((e[8]+e[9])+(e[10]+e[11]))+((e[12]+e[13])+(e[14]+e[15])));
#pragma unroll
      for (int h2 = 0; h2 < 2; ++h2) {
        const int b = 8 * h2;
        // own packs: u0=keys(B+0,1)+4hiK, u1=(B+2,3)+4hiK, u2=(B+8,9)+4hiK, u3=(B+10,11)+4hiK
        u32 u0 = pk2(e[b+0], e[b+1]);
        u32 u1 = pk2(e[b+2], e[b+3]);
        u32 u2 = pk2(e[b+4], e[b+5]);
        u32 u3 = pk2(e[b+6], e[b+7]);
        // send what the partner needs: hi lanes need partner's u2/u3, lo need u0/u1
        u32 sA = hiK ? u0 : u2;
        u32 sB = hiK ? u1 : u3;
        u32 rA = __shfl_xor(sA, 32, 64);   // lo: partner u0 ; hi: partner u2
        u32 rB = __shfl_xor(sB, 32, 64);   // lo: partner u1 ; hi: partner u3
        u32x4 w;
        w[0] = hiK ? rA : u0;
        w[1] = hiK ? rB : u1;
        w[2] = hiK ? u2 : rA;
        w[3] = hiK ? u3 : rB;
        pa[kg * 2 + h2] = __builtin_bit_cast(short8, w);
      }
    }

    // ---- P @ V: acc[dg] over 4 key-slices of 16 ----
    __builtin_amdgcn_s_setprio(1);
#pragma unroll
    for (int dg = 0; dg < 4; ++dg) {
      const short* vr = &Vt[buf][dg * 32 + l31][0];
#pragma unroll
      for (int ks = 0; ks < 4; ++ks) {
        const int c = ((ks << 1) | hiK) ^ l7;
        short8 vb = *reinterpret_cast<const short8*>(vr + c * 8);
        acc[dg] = __builtin_amdgcn_mfma_f32_32x32x16_bf16(pa[ks], vb, acc[dg], 0, 0, 0);
      }
    }
    __builtin_amdgcn_s_setprio(0);
  }

  // ---- epilogue (m is the global running max; acc already on scale m) ----
  const float lsumT = lsum + __shfl_xor(lsum, 32, 64);

#pragma unroll
  for (int r = 0; r < 16; ++r) {
    const int row = (r & 3) + 8 * (r >> 2) + 4 * hiK;
    const size_t ob = ((size_t)(qbase + row) * NH + head) * DD + l31;
#pragma unroll
    for (int dg = 0; dg < 4; ++dg)
      O[ob + dg * 32] = acc[dg][r];
  }

  if (lane < 32) {
    Mo[(size_t)q * NH + head] = m;
    Lo[(size_t)q * NH + head] = lsumT;
  }
}

extern "C" void kernel_launch(void* const* d_in, const int* in_sizes, int n_in,
                              void* d_out, int out_size, void* d_ws, size_t ws_size,
                              hipStream_t stream) {
  const float* Q = (const float*)d_in[0];
  const float* K = (const float*)d_in[1];
  const float* V = (const float*)d_in[2];
  float* O  = (float*)d_out;
  float* Mo = O + (size_t)TT * NH * DD;
  float* Lo = Mo + (size_t)TT * NH;
  short* Kbf  = (short*)d_ws;                          // 4 MB
  short* Vtbf = Kbf + (size_t)NKV * TT * DD;           // 4 MB
  preconv<<<dim3(512), dim3(256), 0, stream>>>(K, V, Kbf, Vtbf);
  attn_fwd<<<dim3(64 * NKV), dim3(256), 0, stream>>>(Q, Kbf, Vtbf, O, Mo, Lo);
}

// Round 7
// 81.445 us; speedup vs baseline: 1.2562x; 1.0848x over previous
//
#include <hip/hip_runtime.h>
#include <hip/hip_bf16.h>

#define TT  2048
#define NH  32
#define NKV 8
#define DD  128
#define KVB 64          // keys per LDS tile
#define THR 8.0f        // defer-max rescale threshold (T13)

typedef __attribute__((ext_vector_type(8)))  short  short8;
typedef __attribute__((ext_vector_type(4)))  float  f32x4;
typedef __attribute__((ext_vector_type(16))) float  f32x16;
typedef unsigned int u32;
typedef __attribute__((ext_vector_type(4)))  u32    u32x4;

static __device__ __forceinline__ short f2bf(float x) {
  __bf16 b = (__bf16)x;                 // RNE f32->bf16
  return __builtin_bit_cast(short, b);
}
static __device__ __forceinline__ short8 cvt8(f32x4 a, f32x4 b) {
  short8 r;
  r[0]=f2bf(a[0]); r[1]=f2bf(a[1]); r[2]=f2bf(a[2]); r[3]=f2bf(a[3]);
  r[4]=f2bf(b[0]); r[5]=f2bf(b[1]); r[6]=f2bf(b[2]); r[7]=f2bf(b[3]);
  return r;
}
static __device__ __forceinline__ u32 pk2(float lo, float hi) {
  const u32 a = (u32)(unsigned short)f2bf(lo);
  const u32 b = (u32)(unsigned short)f2bf(hi);
  return a | (b << 16);
}
static __device__ __forceinline__ void gload_lds16(const short* g, short* l) {
  __builtin_amdgcn_global_load_lds(
      (const __attribute__((address_space(1))) u32*)g,
      (__attribute__((address_space(3))) u32*)l, 16, 0, 0);
}

// ---------------- pre-pass: K -> bf16 [kvh][j][d]; V -> bf16 transposed [kvh][d][j] ----
__global__ __launch_bounds__(256) void preconv(
    const float* __restrict__ K, const float* __restrict__ V,
    short* __restrict__ Kbf, short* __restrict__ Vtbf)
{
  const int t = threadIdx.x;
  if (blockIdx.x >= 256) {
    const int b  = blockIdx.x - 256;
    const int rr = (b << 6) + (t >> 2);      // rr = j*8+kvh
    const int q  = t & 3;
    const int j = rr >> 3, kvh = rr & 7;
    const float* src = K + (size_t)rr * DD + q * 32;
    short* dst = Kbf + ((size_t)kvh * TT + j) * DD + q * 32;
#pragma unroll
    for (int i = 0; i < 4; ++i) {
      f32x4 a  = *reinterpret_cast<const f32x4*>(src + i * 8);
      f32x4 bb = *reinterpret_cast<const f32x4*>(src + i * 8 + 4);
      *reinterpret_cast<short8*>(dst + i * 8) = cvt8(a, bb);
    }
  } else {
    const int kvh = blockIdx.x >> 5, jt = blockIdx.x & 31;
    __shared__ short Vl[64][136];
    const int jl = t >> 2, q = t & 3;
    const float* src = V + ((size_t)(jt * 64 + jl) * NKV + kvh) * DD + q * 32;
#pragma unroll
    for (int i = 0; i < 4; ++i) {
      f32x4 a  = *reinterpret_cast<const f32x4*>(src + i * 8);
      f32x4 bb = *reinterpret_cast<const f32x4*>(src + i * 8 + 4);
      *reinterpret_cast<short8*>(&Vl[jl][q * 32 + i * 8]) = cvt8(a, bb);
    }
    __syncthreads();
    const int d = t >> 1, jh = t & 1;
    short8 o[4];
#pragma unroll
    for (int k = 0; k < 4; ++k)
#pragma unroll
      for (int i = 0; i < 8; ++i)
        o[k][i] = Vl[jh * 32 + k * 8 + i][d];
    short* dst = Vtbf + ((size_t)kvh * DD + d) * TT + jt * 64 + jh * 32;
#pragma unroll
    for (int k = 0; k < 4; ++k)
      *reinterpret_cast<short8*>(dst + k * 8) = o[k];
  }
}

// ---------------- main attention kernel ------------------------------------------
// Block = one kv-head x 32 Q-rows; 8 waves = 4 GQA heads x 2 KEY-HALVES.
// Wave (head, kh) computes QK^T and PV over keys [32kh,32kh+32) of each 64-key
// tile, with an INDEPENDENT per-half online softmax (own m/lsum/tmax/acc);
// halves merged once at the epilogue via LDS with exp(m_h - tmax) scaling
// (this also provably zeroes the fully-masked-half corner at q32 even).
// => 1 barrier/tile, heavy strips run at 2 waves/SIMD, per-wave tile work halved.
// Defer-max (THR=8): rescale only when the half max grows by >8.
// LPT grid order: heaviest strips dispatched first; scheduler backfills.
// K/V double-buffered, staged by global_load_lds, 16B-chunk XOR swizzle
// (phys_chunk = logical ^ (row&7)) pre-applied on the global source address.
// MFMA 32x32x16 layouts: A: lane=A[row=l&31][k=8*(l>>5)+i];
// B: B[k=8*(l>>5)+i][col=l&31]; C/D: col=l&31, row=(reg&3)+8*(reg>>2)+4*(l>>5).
__global__ __launch_bounds__(512, 2) void attn_fwd(
    const float* __restrict__ Q, const short* __restrict__ Kbf,
    const short* __restrict__ Vtbf, float* __restrict__ O,
    float* __restrict__ Mo, float* __restrict__ Lo)
{
  __shared__ __align__(16) short smem[2*KVB*DD + 2*DD*KVB];  // 64KB: Kb | Vt
  __shared__ float sx[3][2][4][32];                          // m / tmax / lsum exchange

  short (*Kb)[KVB][DD] = reinterpret_cast<short(*)[KVB][DD]>(&smem[0]);
  short (*Vt)[DD][KVB] = reinterpret_cast<short(*)[DD][KVB]>(&smem[2*KVB*DD]);

  const int bid  = blockIdx.x;
  const int kvh  = bid & (NKV - 1);          // kvh == XCD id under round-robin
  const int q32  = 63 - (bid >> 3);          // LPT: heaviest first
  const int wv   = threadIdx.x >> 6;         // 0..7
  const int headq= wv & 3;
  const int kh   = wv >> 2;                  // key half of the 64-key tile
  const int lane = threadIdx.x & 63;
  const int l31  = lane & 31;
  const int hiK  = lane >> 5;
  const int l7   = lane & 7;
  const int head = kvh * 4 + headq;
  const int qbase = q32 * 32;
  const int q    = qbase + l31;              // this lane's q-column

  // ---- staging offsets: wave stages K rows [8wv,8wv+8), V d-rows [16wv,16wv+16)
  const int krow0 = 8 * wv + (lane >> 4);
  const int koff0 = krow0 * DD + ((lane & 15) ^ (krow0 & 7)) * 8;
  const int krow1 = krow0 + 4;
  const int koff1 = krow1 * DD + ((lane & 15) ^ (krow1 & 7)) * 8;
  const int vrow0 = 16 * wv + (lane >> 3);
  const int voff0 = vrow0 * TT + ((lane & 7) ^ (lane >> 3)) * 8;
  const int voff1 = voff0 + 8 * TT;

  // ---- Q B-frags: lane holds Q[qbase+l31][ks*16 + 8*hiK + i], ks=0..7 ----
  short8 aq[8];
  {
    const float* qp = Q + ((size_t)q * NH + head) * DD + hiK * 8;
#pragma unroll
    for (int ks = 0; ks < 8; ++ks) {
      const float* p = qp + ks * 16;
      aq[ks] = cvt8(*reinterpret_cast<const f32x4*>(p),
                    *reinterpret_cast<const f32x4*>(p + 4));
    }
  }

  f32x16 acc[4];
#pragma unroll
  for (int i = 0; i < 4; ++i) acc[i] = (f32x16)0.0f;
  float m = -INFINITY, tmaxh = -INFINITY, lsum = 0.0f;

  const int ntiles = (q32 >> 1) + 1;   // ceil((qbase+32)/64)

  const short* kgp = Kbf + (size_t)kvh * TT * DD;
  const short* vgp = Vtbf + (size_t)kvh * DD * TT;

  // ---- prologue: DMA tile 0 into buffer 0 ----
  gload_lds16(kgp + koff0, &Kb[0][8 * wv][0]);
  gload_lds16(kgp + koff1, &Kb[0][8 * wv + 4][0]);
  gload_lds16(vgp + voff0, &Vt[0][16 * wv][0]);
  gload_lds16(vgp + voff1, &Vt[0][16 * wv + 8][0]);
  kgp += (size_t)KVB * DD;
  vgp += KVB;

  for (int jt = 0; jt < ntiles; ++jt) {
    const int j0  = jt << 6;
    const int buf = jt & 1;

    __syncthreads();   // drains own DMA (vmcnt0); prev buffer free for overwrite

    // ---- QK^T on this wave's key half: st = S^T[key=32kh+row(r,hiK)][q=l31] ----
    f32x16 st = (f32x16)0.0f;
    const short* kr = &Kb[buf][kh * 32 + l31][0];
    __builtin_amdgcn_s_setprio(1);
#pragma unroll
    for (int ks = 0; ks < 8; ++ks) {
      const int c = ((ks << 1) | hiK) ^ l7;
      short8 kb = *reinterpret_cast<const short8*>(kr + c * 8);
      st = __builtin_amdgcn_mfma_f32_32x32x16_bf16(kb, aq[ks], st, 0, 0, 0);
    }
    __builtin_amdgcn_s_setprio(0);

    // ---- DMA tile jt+1 into buf^1 (lands during softmax+PV+next barrier) ----
    if (jt + 1 < ntiles) {
      const int nb = buf ^ 1;
      gload_lds16(kgp + koff0, &Kb[nb][8 * wv][0]);
      gload_lds16(kgp + koff1, &Kb[nb][8 * wv + 4][0]);
      gload_lds16(vgp + voff0, &Vt[nb][16 * wv][0]);
      gload_lds16(vgp + voff1, &Vt[nb][16 * wv + 8][0]);
      kgp += (size_t)KVB * DD;
      vgp += KVB;
    }

    // ---- causal mask: only the last tile can cross the diagonal ----
    if (jt == ntiles - 1) {
#pragma unroll
      for (int r = 0; r < 16; ++r) {
        const int key = j0 + kh * 32 + (r & 3) + 8 * (r >> 2) + 4 * hiK;
        if (key > q) st[r] = -1.0e10f;
      }
    }

    // ---- half-tile max (lane-local + lane^32 merge) ----
    float mx = st[0];
#pragma unroll
    for (int r = 1; r < 16; ++r) mx = fmaxf(mx, st[r]);
    mx = fmaxf(mx, __shfl_xor(mx, 32, 64));
    tmaxh = fmaxf(tmaxh, mx);

    // ---- defer-max: rescale only when the running max grows by >THR ----
    if (__any(mx > m + THR)) {
      const float mn = fmaxf(m, mx);
      const float sc = __expf(m - mn);
      m = mn;
      lsum *= sc;
#pragma unroll
      for (int r = 0; r < 16; ++r) {
        const float sf = __shfl(sc, (r & 3) + 8 * (r >> 2) + 4 * hiK, 64);
        acc[0][r] *= sf; acc[1][r] *= sf; acc[2][r] *= sf; acc[3][r] *= sf;
      }
    }

    // ---- P = exp(S-m) (bounded by e^THR); pack to PV A-frags via lane^32 ----
    float e[16];
#pragma unroll
    for (int r = 0; r < 16; ++r) e[r] = __expf(st[r] - m);
    lsum += (((e[0]+e[1])+(e[2]+e[3]))+((e[4]+e[5])+(e[6]+e[7])))
          + (((e[8]+e[9])+(e[10]+e[11]))+((e[12]+e[13])+(e[14]+e[15])));

    short8 pa[2];
#pragma unroll
    for (int h2 = 0; h2 < 2; ++h2) {
      const int b = 8 * h2;
      u32 u0 = pk2(e[b+0], e[b+1]);
      u32 u1 = pk2(e[b+2], e[b+3]);
      u32 u2 = pk2(e[b+4], e[b+5]);
      u32 u3 = pk2(e[b+6], e[b+7]);
      u32 sA = hiK ? u0 : u2;
      u32 sB = hiK ? u1 : u3;
      u32 rA = __shfl_xor(sA, 32, 64);
      u32 rB = __shfl_xor(sB, 32, 64);
      u32x4 w;
      w[0] = hiK ? rA : u0;
      w[1] = hiK ? rB : u1;
      w[2] = hiK ? u2 : rA;
      w[3] = hiK ? u3 : rB;
      pa[h2] = __builtin_bit_cast(short8, w);
    }

    // ---- P @ V over this wave's 2 key-slices ----
    __builtin_amdgcn_s_setprio(1);
#pragma unroll
    for (int dg = 0; dg < 4; ++dg) {
      const short* vr = &Vt[buf][dg * 32 + l31][0];
#pragma unroll
      for (int h2 = 0; h2 < 2; ++h2) {
        const int ksv = 2 * kh + h2;
        const int c = ((ksv << 1) | hiK) ^ l7;
        short8 vb = *reinterpret_cast<const short8*>(vr + c * 8);
        acc[dg] = __builtin_amdgcn_mfma_f32_32x32x16_bf16(pa[h2], vb, acc[dg], 0, 0, 0);
      }
    }
    __builtin_amdgcn_s_setprio(0);
  }

  // ---- epilogue: merge the two key-halves ----
  const float lw = lsum + __shfl_xor(lsum, 32, 64);
  __syncthreads();                     // all PV done; K/V LDS is dead now
  if (lane < 32) {
    sx[0][kh][headq][lane] = m;
    sx[1][kh][headq][lane] = tmaxh;
    sx[2][kh][headq][lane] = lw;
  }
  __syncthreads();
  const float mo   = sx[0][kh ^ 1][headq][l31];
  const float to   = sx[1][kh ^ 1][headq][l31];
  const float lo2  = sx[2][kh ^ 1][headq][l31];
  const float tmax = fmaxf(tmaxh, to);
  const float fsA  = __expf(m - tmax);          // own-half scale to true max
  const float ltot = lw * fsA + lo2 * __expf(mo - tmax);

  float* mbuf = reinterpret_cast<float*>(&smem[0]);   // 64KB = 4 heads x 32q x 128d
  if (kh == 1) {
#pragma unroll
    for (int r = 0; r < 16; ++r) {
      const int row = (r & 3) + 8 * (r >> 2) + 4 * hiK;
      const float sfr = __shfl(fsA, row, 64);
#pragma unroll
      for (int dg = 0; dg < 4; ++dg)
        mbuf[headq * 4096 + row * 128 + dg * 32 + l31] = acc[dg][r] * sfr;
    }
  }
  __syncthreads();
  if (kh == 0) {
#pragma unroll
    for (int r = 0; r < 16; ++r) {
      const int row = (r & 3) + 8 * (r >> 2) + 4 * hiK;
      const float sfr = __shfl(fsA, row, 64);
      const size_t ob = ((size_t)(qbase + row) * NH + head) * DD + l31;
#pragma unroll
      for (int dg = 0; dg < 4; ++dg)
        O[ob + dg * 32] = acc[dg][r] * sfr + mbuf[headq * 4096 + row * 128 + dg * 32 + l31];
    }
    if (lane < 32) {
      Mo[(size_t)q * NH + head] = tmax;
      Lo[(size_t)q * NH + head] = ltot;
    }
  }
}

extern "C" void kernel_launch(void* const* d_in, const int* in_sizes, int n_in,
                              void* d_out, int out_size, void* d_ws, size_t ws_size,
                              hipStream_t stream) {
  const float* Q = (const float*)d_in[0];
  const float* K = (const float*)d_in[1];
  const float* V = (const float*)d_in[2];
  float* O  = (float*)d_out;
  float* Mo = O + (size_t)TT * NH * DD;
  float* Lo = Mo + (size_t)TT * NH;
  short* Kbf  = (short*)d_ws;                          // 4 MB
  short* Vtbf = Kbf + (size_t)NKV * TT * DD;           // 4 MB
  preconv<<<dim3(512), dim3(256), 0, stream>>>(K, V, Kbf, Vtbf);
  attn_fwd<<<dim3(64 * NKV), dim3(512), 0, stream>>>(Q, Kbf, Vtbf, O, Mo, Lo);
}